// Round 3
// baseline (13.165 us; speedup 1.0000x reference)
//
#include <hip/hip_runtime.h>
#include <math.h>

// Analytic simulation:
//  - per-qubit product states tracked as real Bloch vectors (SO(3) rotations),
//  - layer-2 observables O_q = U^dag Z U = n·sigma with n = Rx(-a)Ry(-b) z_hat,
//  - CNOT-ring pullback of each Pauli string via stabilizer (symplectic) update,
//  - expectation of a Pauli string on a product state = product of Bloch components.
// Wave-local version: each expectation group (one wave) computes its own Bloch /
// observable vectors into wave-private LDS -> no block barrier between setup and
// string evaluation (wave lockstep + lgkmcnt(0) suffices). Head weights are
// prefetched into registers at entry to hide HBM latency under phases A-C.

__device__ __forceinline__ void brx(float t, float& x, float& y, float& z) {
  float s, c; sincosf(t, &s, &c);
  float y2 = c * y - s * z;
  z = s * y + c * z;
  y = y2;
  (void)x;
}
__device__ __forceinline__ void bry(float t, float& x, float& y, float& z) {
  float s, c; sincosf(t, &s, &c);
  float z2 = c * z - s * x;
  x = s * z + c * x;
  z = z2;
  (void)y;
}
__device__ __forceinline__ void brz(float t, float& x, float& y, float& z) {
  float s, c; sincosf(t, &s, &c);
  float x2 = c * x - s * y;
  y = s * x + c * y;
  x = x2;
  (void)z;
}

__global__ __launch_bounds__(512) void qie_kernel(
    const float* __restrict__ x,     // [8,16,4,3]
    const float* __restrict__ posw,  // [16,2]
    const float* __restrict__ l1w,   // [20,3]
    const float* __restrict__ l2w,   // [16,3]
    const float* __restrict__ hw,    // [512,4]
    const float* __restrict__ hb,    // [512]
    float* __restrict__ out)         // [8,512]
{
  const int img = blockIdx.x;
  const int tid = threadIdx.x;
  const int wid = tid >> 6, lane = tid & 63;

  // Prefetch head weights into registers; overlaps with phases A-C.
  const float hw0 = hw[tid * 4 + 0];
  const float hw1 = hw[tid * 4 + 1];
  const float hw2 = hw[tid * 4 + 2];
  const float hw3 = hw[tid * 4 + 3];
  const float hbb = hb[tid];

  __shared__ float wbl[7][20][3];  // per-wave Bloch vectors
  __shared__ float wnv[7][4][3];   // per-wave observable vectors (by wire offset k)
  __shared__ float eg[7];          // group expectations
  __shared__ float red[8];         // norm partials

  // g0..g3: Efull[b] wires {0..3}; g4: eA wires {1,2,3}; g5: e1 {0,1}; g6: e2 {0,1,2}.
  const int g_nw[7] = {4, 4, 4, 4, 3, 2, 3};
  const int g_qb[7] = {0, 1, 2, 3, 0, 0, 0};
  const int g_w0[7] = {0, 0, 0, 0, 1, 0, 0};

  float acc = 0.0f;
  if (wid < 7) {
    const int nw = g_nw[wid], qb = g_qb[wid], w0 = g_w0[wid];

    // ---- wave-local setup ----
    if (lane < 20) {
      const int i = lane;
      const int p = 4 * qb + i / 5, j = i % 5;
      float nx = 0.f, ny = 0.f, nz = 1.f;  // |0> = z_hat
      if (j < 4) {
        const float* a = x + ((img * 16 + p) * 4 + j) * 3;
        brx(a[0], nx, ny, nz);
        bry(a[1], nx, ny, nz);
        brz(a[2], nx, ny, nz);
      } else {
        brx(posw[p * 2 + 0], nx, ny, nz);
        bry(posw[p * 2 + 1], nx, ny, nz);
      }
      brx(l1w[i * 3 + 0], nx, ny, nz);
      bry(l1w[i * 3 + 1], nx, ny, nz);
      brz(l1w[i * 3 + 2], nx, ny, nz);
      wbl[wid][i][0] = nx; wbl[wid][i][1] = ny; wbl[wid][i][2] = nz;
    } else if (lane < 24) {
      const int k = lane - 20;
      if (k < nw) {
        const int q = 4 * qb + w0 + k;  // O_q = n.sigma, n = Rx(-a)Ry(-b) z_hat
        float sa, ca, sb, cb;
        sincosf(l2w[q * 3 + 0], &sa, &ca);
        sincosf(l2w[q * 3 + 1], &sb, &cb);
        wnv[wid][k][0] = -sb;
        wnv[wid][k][1] = sa * cb;
        wnv[wid][k][2] = ca * cb;
      }
    }
    // Wave-lockstep visibility: drain LDS writes, forbid reordering.
    __builtin_amdgcn_wave_barrier();
    asm volatile("s_waitcnt lgkmcnt(0)" ::: "memory");
    __builtin_amdgcn_sched_barrier(0);

    int nstr = 1;
    for (int k = 0; k < nw; ++k) nstr *= 3;
    for (int t = lane; t < nstr; t += 64) {
      unsigned xm = 0, zm = 0;
      float coeff = 1.0f;
      int tt = t;
      for (int k = 0; k < nw; ++k) {
        const int w = w0 + k;
        const int d = tt % 3;  // 0=X,1=Y,2=Z
        tt /= 3;
        coeff *= wnv[wid][k][d];
        if (d != 2) xm |= 1u << w;
        if (d != 0) zm |= 1u << w;
      }
      // Pull back through CNOT ring: conjugate by C(19,0) first ... C(0,1) last.
      unsigned sgn = 0;
      for (int c = 19; c >= 0; --c) {
        const int tq = (c + 1) % 20;
        const unsigned xc = (xm >> c) & 1u, zc = (zm >> c) & 1u;
        const unsigned xt = (xm >> tq) & 1u, zt = (zm >> tq) & 1u;
        sgn ^= xc & zt & (xt ^ zc ^ 1u);
        xm ^= xc << tq;  // x_t ^= x_c
        zm ^= zt << c;   // z_c ^= z_t
      }
      float val = sgn ? -coeff : coeff;
      unsigned um = xm | zm;
      while (um) {
        const int i = __builtin_ctz(um);
        um &= um - 1;
        const unsigned xi = (xm >> i) & 1u, zi = (zm >> i) & 1u;
        val *= wbl[wid][i][xi ? (zi ? 1 : 0) : 2];
      }
      acc += val;
    }
  }
  for (int off = 32; off; off >>= 1) acc += __shfl_xor(acc, off, 64);
  if (wid < 7 && lane == 0) eg[wid] = acc;
  __syncthreads();

  // ---- head + L2 normalize ----
  const float q0 = eg[4] * eg[1] * eg[2] * eg[3];  // e0
  const float q1 = eg[5];                          // e1
  const float q2 = eg[6];                          // e2
  const float q3 = eg[0];                          // e3 = Efull[0]

  float y = q0 * hw0 + q1 * hw1 + q2 * hw2 + q3 * hw3 + hbb;
  float ss = y * y;
  for (int off = 32; off; off >>= 1) ss += __shfl_xor(ss, off, 64);
  if (lane == 0) red[wid] = ss;
  __syncthreads();
  const float s = red[0] + red[1] + red[2] + red[3] + red[4] + red[5] + red[6] + red[7];
  const float rn = 1.0f / fmaxf(sqrtf(s), 1e-12f);
  out[img * 512 + tid] = y * rn;
}

extern "C" void kernel_launch(void* const* d_in, const int* in_sizes, int n_in,
                              void* d_out, int out_size, void* d_ws, size_t ws_size,
                              hipStream_t stream) {
  const float* x    = (const float*)d_in[0];  // [8,16,4,3]
  const float* posw = (const float*)d_in[1];  // [16,2]
  const float* l1w  = (const float*)d_in[2];  // [20,3]
  const float* l2w  = (const float*)d_in[3];  // [16,3]
  const float* hw   = (const float*)d_in[4];  // [512,4]
  const float* hb   = (const float*)d_in[5];  // [512]
  float* out = (float*)d_out;                 // [8,512]
  qie_kernel<<<8, 512, 0, stream>>>(x, posw, l1w, l2w, hw, hb, out);
}

// Round 4
// 11.920 us; speedup vs baseline: 1.1045x; 1.1045x over previous
//
#include <hip/hip_runtime.h>
#include <math.h>

// Analytic simulation:
//  - per-qubit product states tracked as real Bloch vectors (SO(3) rotations),
//  - layer-2 observables O_q = U^dag Z U = n·sigma with n = Rx(-a)Ry(-b) z_hat,
//  - CNOT-ring pullback of each Pauli string precomputed at COMPILE TIME
//    (symplectic conjugation is data-independent) into a 7 KB .rodata table,
//  - expectation of a Pauli string on a product state = product of Bloch components.
// Structure = round-2 winner (shared setup, 3 block barriers) + entry prefetch of
// table entries and head weights (latency hidden under phase-A sincosf chain).

struct STab {
  unsigned lo[7][128];  // xm(20b) | sgn<<20 | digits<<21 (2b per wire)
  unsigned hi[7][128];  // zm(20b)
};

constexpr STab make_tab() {
  STab T{};
  const int g_nw[7] = {4, 4, 4, 4, 3, 2, 3};
  const int g_w0[7] = {0, 0, 0, 0, 1, 0, 0};
  for (int g = 0; g < 7; ++g) {
    const int nw = g_nw[g], w0 = g_w0[g];
    int nstr = 1;
    for (int k = 0; k < nw; ++k) nstr *= 3;
    for (int t = 0; t < nstr; ++t) {
      unsigned xm = 0, zm = 0, dg = 0;
      int tt = t;
      for (int k = 0; k < nw; ++k) {
        const int d = tt % 3;  // 0=X,1=Y,2=Z
        tt /= 3;
        dg |= (unsigned)d << (2 * k);
        const int w = w0 + k;
        if (d != 2) xm |= 1u << w;
        if (d != 0) zm |= 1u << w;
      }
      // Pull back through CNOT ring: conjugate by C(19,0) first ... C(0,1) last.
      unsigned sgn = 0;
      for (int c = 19; c >= 0; --c) {
        const int tq = (c + 1) % 20;
        const unsigned xc = (xm >> c) & 1u, zc = (zm >> c) & 1u;
        const unsigned xt = (xm >> tq) & 1u, zt = (zm >> tq) & 1u;
        sgn ^= xc & zt & (xt ^ zc ^ 1u);
        xm ^= xc << tq;  // x_t ^= x_c
        zm ^= zt << c;   // z_c ^= z_t
      }
      T.lo[g][t] = xm | (sgn << 20) | (dg << 21);
      T.hi[g][t] = zm;
    }
  }
  return T;
}

__device__ constexpr STab TAB = make_tab();

__device__ __forceinline__ void brx(float t, float& x, float& y, float& z) {
  float s, c; sincosf(t, &s, &c);
  float y2 = c * y - s * z;
  z = s * y + c * z;
  y = y2;
  (void)x;
}
__device__ __forceinline__ void bry(float t, float& x, float& y, float& z) {
  float s, c; sincosf(t, &s, &c);
  float z2 = c * z - s * x;
  x = s * z + c * x;
  z = z2;
  (void)y;
}
__device__ __forceinline__ void brz(float t, float& x, float& y, float& z) {
  float s, c; sincosf(t, &s, &c);
  float x2 = c * x - s * y;
  y = s * x + c * y;
  x = x2;
  (void)z;
}

__global__ __launch_bounds__(512) void qie_kernel(
    const float* __restrict__ x,     // [8,16,4,3]
    const float* __restrict__ posw,  // [16,2]
    const float* __restrict__ l1w,   // [20,3]
    const float* __restrict__ l2w,   // [16,3]
    const float* __restrict__ hw,    // [512,4]
    const float* __restrict__ hb,    // [512]
    float* __restrict__ out)         // [8,512]
{
  const int img = blockIdx.x;
  const int tid = threadIdx.x;
  const int wid = tid >> 6, lane = tid & 63;

  // Entry prefetch: head weights + this lane's two Pauli-string table entries.
  // Latency hides under phase A's sincosf chain.
  const float hw0 = hw[tid * 4 + 0];
  const float hw1 = hw[tid * 4 + 1];
  const float hw2 = hw[tid * 4 + 2];
  const float hw3 = hw[tid * 4 + 3];
  const float hbb = hb[tid];
  unsigned lo1 = 0, hi1 = 0, lo2 = 0, hi2 = 0;
  if (wid < 7) {
    lo1 = TAB.lo[wid][lane];
    hi1 = TAB.hi[wid][lane];
    lo2 = TAB.lo[wid][lane + 64];
    hi2 = TAB.hi[wid][lane + 64];
  }

  __shared__ float bl[4][20][3];  // Bloch vectors: [block][qubit][x,y,z]
  __shared__ float nv[16][3];     // observable Bloch vectors
  __shared__ float eg[7];         // group expectations
  __shared__ float red[8];        // norm partials

  // ---- Phase A: per-qubit Bloch vectors (threads 0..79) ----
  if (tid < 80) {
    const int b = tid / 20, i = tid % 20;
    const int p = 4 * b + i / 5, j = i % 5;
    float nx = 0.f, ny = 0.f, nz = 1.f;  // |0> = z_hat
    if (j < 4) {
      const float* a = x + ((img * 16 + p) * 4 + j) * 3;
      brx(a[0], nx, ny, nz);
      bry(a[1], nx, ny, nz);
      brz(a[2], nx, ny, nz);
    } else {
      brx(posw[p * 2 + 0], nx, ny, nz);
      bry(posw[p * 2 + 1], nx, ny, nz);
    }
    brx(l1w[i * 3 + 0], nx, ny, nz);
    bry(l1w[i * 3 + 1], nx, ny, nz);
    brz(l1w[i * 3 + 2], nx, ny, nz);
    bl[b][i][0] = nx; bl[b][i][1] = ny; bl[b][i][2] = nz;
  } else if (tid < 96) {
    // ---- Phase B: O_q = n·sigma, n = Rx(-a)Ry(-b) z_hat (Rz drops out) ----
    const int q = tid - 80;
    float sa, ca, sb, cb;
    sincosf(l2w[q * 3 + 0], &sa, &ca);
    sincosf(l2w[q * 3 + 1], &sb, &cb);
    nv[q][0] = -sb;       // X coeff
    nv[q][1] = sa * cb;   // Y coeff
    nv[q][2] = ca * cb;   // Z coeff
  }
  __syncthreads();

  // ---- Phase C: 7 expectation groups, one wave each ----
  // g0..g3: Efull[b] wires {0..3}; g4: eA wires {1,2,3}; g5: e1 {0,1}; g6: e2 {0,1,2}.
  float acc = 0.0f;
  if (wid < 7) {
    const int g_nw[7] = {4, 4, 4, 4, 3, 2, 3};
    const int g_qb[7] = {0, 1, 2, 3, 0, 0, 0};
    const int g_w0[7] = {0, 0, 0, 0, 1, 0, 0};
    const int g_ns[7] = {81, 81, 81, 81, 27, 9, 27};
    const int nw = g_nw[wid], qb = g_qb[wid], w0 = g_w0[wid], nstr = g_ns[wid];

    auto eval = [&](unsigned lo, unsigned hi) -> float {
      float coeff = 1.0f;
      const unsigned dg = lo >> 21;
      for (int k = 0; k < nw; ++k)
        coeff *= nv[4 * qb + w0 + k][(dg >> (2 * k)) & 3u];
      float val = ((lo >> 20) & 1u) ? -coeff : coeff;
      const unsigned xm = lo & 0xFFFFFu, zm = hi;
      unsigned um = xm | zm;
      while (um) {
        const int i = __builtin_ctz(um);
        um &= um - 1;
        const unsigned xi = (xm >> i) & 1u, zi = (zm >> i) & 1u;
        val *= bl[qb][i][xi ? (zi ? 1 : 0) : 2];
      }
      return val;
    };

    if (lane < nstr) acc = eval(lo1, hi1);
    if (lane + 64 < nstr) acc += eval(lo2, hi2);
  }
  for (int off = 32; off; off >>= 1) acc += __shfl_xor(acc, off, 64);
  if (wid < 7 && lane == 0) eg[wid] = acc;
  __syncthreads();

  // ---- head + L2 normalize ----
  const float q0 = eg[4] * eg[1] * eg[2] * eg[3];  // e0
  const float q1 = eg[5];                          // e1
  const float q2 = eg[6];                          // e2
  const float q3 = eg[0];                          // e3 = Efull[0]

  float y = q0 * hw0 + q1 * hw1 + q2 * hw2 + q3 * hw3 + hbb;
  float ss = y * y;
  for (int off = 32; off; off >>= 1) ss += __shfl_xor(ss, off, 64);
  if (lane == 0) red[wid] = ss;
  __syncthreads();
  const float s = red[0] + red[1] + red[2] + red[3] + red[4] + red[5] + red[6] + red[7];
  const float rn = 1.0f / fmaxf(sqrtf(s), 1e-12f);
  out[img * 512 + tid] = y * rn;
}

extern "C" void kernel_launch(void* const* d_in, const int* in_sizes, int n_in,
                              void* d_out, int out_size, void* d_ws, size_t ws_size,
                              hipStream_t stream) {
  const float* x    = (const float*)d_in[0];  // [8,16,4,3]
  const float* posw = (const float*)d_in[1];  // [16,2]
  const float* l1w  = (const float*)d_in[2];  // [20,3]
  const float* l2w  = (const float*)d_in[3];  // [16,3]
  const float* hw   = (const float*)d_in[4];  // [512,4]
  const float* hb   = (const float*)d_in[5];  // [512]
  float* out = (float*)d_out;                 // [8,512]
  qie_kernel<<<8, 512, 0, stream>>>(x, posw, l1w, l2w, hw, hb, out);
}

// Round 5
// 10.705 us; speedup vs baseline: 1.2299x; 1.1135x over previous
//
#include <hip/hip_runtime.h>
#include <math.h>

// Analytic simulation:
//  - per-qubit product states tracked as real Bloch vectors (SO(3) rotations),
//  - layer-2 observables O_q = U^dag Z U = n·sigma with n = Rx(-a)Ry(-b) z_hat,
//  - CNOT-ring pullback of each Pauli string precomputed at COMPILE TIME
//    (symplectic conjugation is data-independent) into a 7 KB .rodata table,
//  - expectation of a Pauli string on a product state = product of Bloch components.
// R5: hardware v_sin/v_cos (inputs are |t|<~6 rad, well inside HW range in
// revolutions; ~2 ulp fine for 3.5e-3 threshold) -> phase-A dependent chain
// shrinks ~3x. rsqrt for the final norm.

struct STab {
  unsigned lo[7][128];  // xm(20b) | sgn<<20 | digits<<21 (2b per wire)
  unsigned hi[7][128];  // zm(20b)
};

constexpr STab make_tab() {
  STab T{};
  const int g_nw[7] = {4, 4, 4, 4, 3, 2, 3};
  const int g_w0[7] = {0, 0, 0, 0, 1, 0, 0};
  for (int g = 0; g < 7; ++g) {
    const int nw = g_nw[g], w0 = g_w0[g];
    int nstr = 1;
    for (int k = 0; k < nw; ++k) nstr *= 3;
    for (int t = 0; t < nstr; ++t) {
      unsigned xm = 0, zm = 0, dg = 0;
      int tt = t;
      for (int k = 0; k < nw; ++k) {
        const int d = tt % 3;  // 0=X,1=Y,2=Z
        tt /= 3;
        dg |= (unsigned)d << (2 * k);
        const int w = w0 + k;
        if (d != 2) xm |= 1u << w;
        if (d != 0) zm |= 1u << w;
      }
      // Pull back through CNOT ring: conjugate by C(19,0) first ... C(0,1) last.
      unsigned sgn = 0;
      for (int c = 19; c >= 0; --c) {
        const int tq = (c + 1) % 20;
        const unsigned xc = (xm >> c) & 1u, zc = (zm >> c) & 1u;
        const unsigned xt = (xm >> tq) & 1u, zt = (zm >> tq) & 1u;
        sgn ^= xc & zt & (xt ^ zc ^ 1u);
        xm ^= xc << tq;  // x_t ^= x_c
        zm ^= zt << c;   // z_c ^= z_t
      }
      T.lo[g][t] = xm | (sgn << 20) | (dg << 21);
      T.hi[g][t] = zm;
    }
  }
  return T;
}

__device__ constexpr STab TAB = make_tab();

// Hardware sin/cos: v_sin_f32/v_cos_f32 take revolutions. Inputs here are
// |t| <~ 6 rad (<1 revolution) -- no range reduction needed, ~2 ulp.
__device__ __forceinline__ void fsc(float t, float& s, float& c) {
  const float r = t * 0.15915494309189535f;  // 1/(2*pi)
  s = __builtin_amdgcn_sinf(r);
  c = __builtin_amdgcn_cosf(r);
}

__device__ __forceinline__ void brx(float t, float& x, float& y, float& z) {
  float s, c; fsc(t, s, c);
  float y2 = c * y - s * z;
  z = s * y + c * z;
  y = y2;
  (void)x;
}
__device__ __forceinline__ void bry(float t, float& x, float& y, float& z) {
  float s, c; fsc(t, s, c);
  float z2 = c * z - s * x;
  x = s * z + c * x;
  z = z2;
  (void)y;
}
__device__ __forceinline__ void brz(float t, float& x, float& y, float& z) {
  float s, c; fsc(t, s, c);
  float x2 = c * x - s * y;
  y = s * x + c * y;
  x = x2;
  (void)z;
}

__global__ __launch_bounds__(512) void qie_kernel(
    const float* __restrict__ x,     // [8,16,4,3]
    const float* __restrict__ posw,  // [16,2]
    const float* __restrict__ l1w,   // [20,3]
    const float* __restrict__ l2w,   // [16,3]
    const float* __restrict__ hw,    // [512,4]
    const float* __restrict__ hb,    // [512]
    float* __restrict__ out)         // [8,512]
{
  const int img = blockIdx.x;
  const int tid = threadIdx.x;
  const int wid = tid >> 6, lane = tid & 63;

  // Entry prefetch: head weights + this lane's two Pauli-string table entries.
  const float hw0 = hw[tid * 4 + 0];
  const float hw1 = hw[tid * 4 + 1];
  const float hw2 = hw[tid * 4 + 2];
  const float hw3 = hw[tid * 4 + 3];
  const float hbb = hb[tid];
  unsigned lo1 = 0, hi1 = 0, lo2 = 0, hi2 = 0;
  if (wid < 7) {
    lo1 = TAB.lo[wid][lane];
    hi1 = TAB.hi[wid][lane];
    lo2 = TAB.lo[wid][lane + 64];
    hi2 = TAB.hi[wid][lane + 64];
  }

  __shared__ float bl[4][20][3];  // Bloch vectors: [block][qubit][x,y,z]
  __shared__ float nv[16][3];     // observable Bloch vectors
  __shared__ float eg[7];         // group expectations
  __shared__ float red[8];        // norm partials

  // ---- Phase A: per-qubit Bloch vectors (threads 0..79) ----
  if (tid < 80) {
    const int b = tid / 20, i = tid % 20;
    const int p = 4 * b + i / 5, j = i % 5;
    float nx = 0.f, ny = 0.f, nz = 1.f;  // |0> = z_hat
    if (j < 4) {
      const float* a = x + ((img * 16 + p) * 4 + j) * 3;
      brx(a[0], nx, ny, nz);
      bry(a[1], nx, ny, nz);
      brz(a[2], nx, ny, nz);
    } else {
      brx(posw[p * 2 + 0], nx, ny, nz);
      bry(posw[p * 2 + 1], nx, ny, nz);
    }
    brx(l1w[i * 3 + 0], nx, ny, nz);
    bry(l1w[i * 3 + 1], nx, ny, nz);
    brz(l1w[i * 3 + 2], nx, ny, nz);
    bl[b][i][0] = nx; bl[b][i][1] = ny; bl[b][i][2] = nz;
  } else if (tid < 96) {
    // ---- Phase B: O_q = n·sigma, n = Rx(-a)Ry(-b) z_hat (Rz drops out) ----
    const int q = tid - 80;
    float sa, ca, sb, cb;
    fsc(l2w[q * 3 + 0], sa, ca);
    fsc(l2w[q * 3 + 1], sb, cb);
    nv[q][0] = -sb;       // X coeff
    nv[q][1] = sa * cb;   // Y coeff
    nv[q][2] = ca * cb;   // Z coeff
  }
  __syncthreads();

  // ---- Phase C: 7 expectation groups, one wave each ----
  // g0..g3: Efull[b] wires {0..3}; g4: eA wires {1,2,3}; g5: e1 {0,1}; g6: e2 {0,1,2}.
  float acc = 0.0f;
  if (wid < 7) {
    const int g_nw[7] = {4, 4, 4, 4, 3, 2, 3};
    const int g_qb[7] = {0, 1, 2, 3, 0, 0, 0};
    const int g_w0[7] = {0, 0, 0, 0, 1, 0, 0};
    const int g_ns[7] = {81, 81, 81, 81, 27, 9, 27};
    const int nw = g_nw[wid], qb = g_qb[wid], w0 = g_w0[wid], nstr = g_ns[wid];

    auto eval = [&](unsigned lo, unsigned hi) -> float {
      float coeff = 1.0f;
      const unsigned dg = lo >> 21;
      for (int k = 0; k < nw; ++k)
        coeff *= nv[4 * qb + w0 + k][(dg >> (2 * k)) & 3u];
      float val = ((lo >> 20) & 1u) ? -coeff : coeff;
      const unsigned xm = lo & 0xFFFFFu, zm = hi;
      unsigned um = xm | zm;
      while (um) {
        const int i = __builtin_ctz(um);
        um &= um - 1;
        const unsigned xi = (xm >> i) & 1u, zi = (zm >> i) & 1u;
        val *= bl[qb][i][xi ? (zi ? 1 : 0) : 2];
      }
      return val;
    };

    if (lane < nstr) acc = eval(lo1, hi1);
    if (lane + 64 < nstr) acc += eval(lo2, hi2);
  }
  for (int off = 32; off; off >>= 1) acc += __shfl_xor(acc, off, 64);
  if (wid < 7 && lane == 0) eg[wid] = acc;
  __syncthreads();

  // ---- head + L2 normalize ----
  const float q0 = eg[4] * eg[1] * eg[2] * eg[3];  // e0
  const float q1 = eg[5];                          // e1
  const float q2 = eg[6];                          // e2
  const float q3 = eg[0];                          // e3 = Efull[0]

  float y = q0 * hw0 + q1 * hw1 + q2 * hw2 + q3 * hw3 + hbb;
  float ss = y * y;
  for (int off = 32; off; off >>= 1) ss += __shfl_xor(ss, off, 64);
  if (lane == 0) red[wid] = ss;
  __syncthreads();
  const float s = red[0] + red[1] + red[2] + red[3] + red[4] + red[5] + red[6] + red[7];
  const float rn = __builtin_amdgcn_rsqf(fmaxf(s, 1e-24f));
  out[img * 512 + tid] = y * rn;
}

extern "C" void kernel_launch(void* const* d_in, const int* in_sizes, int n_in,
                              void* d_out, int out_size, void* d_ws, size_t ws_size,
                              hipStream_t stream) {
  const float* x    = (const float*)d_in[0];  // [8,16,4,3]
  const float* posw = (const float*)d_in[1];  // [16,2]
  const float* l1w  = (const float*)d_in[2];  // [20,3]
  const float* l2w  = (const float*)d_in[3];  // [16,3]
  const float* hw   = (const float*)d_in[4];  // [512,4]
  const float* hb   = (const float*)d_in[5];  // [512]
  float* out = (float*)d_out;                 // [8,512]
  qie_kernel<<<8, 512, 0, stream>>>(x, posw, l1w, l2w, hw, hb, out);
}